// Round 12
// baseline (234.198 us; speedup 1.0000x reference)
//
#include <hip/hip_runtime.h>
#include <math.h>

#define N_ATOMS 16384
#define APC 64
#define N_CONF 256
#define N_MOL 64
#define DEG 32
#define NEDGE (N_ATOMS * DEG)
#define H 128
#define G 50
#define NL 6
#define TP0 512          // fp32 source table points
#define TPB 4096         // fp16 nearest table points
#define CUTOFF 10.0f

typedef __attribute__((ext_vector_type(8))) _Float16 half8_t;
typedef __attribute__((ext_vector_type(4))) _Float16 half4_t;
typedef __attribute__((ext_vector_type(2))) _Float16 half2_t;
typedef __attribute__((ext_vector_type(4))) float f32x4;

__device__ __forceinline__ float ssp_f(float x) {
  float e = __expf(-fabsf(x));
  return fmaxf(x, 0.f) + __logf(1.f + e) - 0.69314718055994531f;
}

// pack 4 fp32 -> 4 fp16 (RNE) in a uint2 — vector bit_cast, no union/alloca
__device__ __forceinline__ uint2 pack4h(const f32x4 v) {
  half4_t h;
  h[0] = (_Float16)v[0];
  h[1] = (_Float16)v[1];
  h[2] = (_Float16)v[2];
  h[3] = (_Float16)v[3];
  return __builtin_bit_cast(uint2, h);
}
__device__ __forceinline__ void unpack4h(uint2 u, float* o) {
  half4_t h = __builtin_bit_cast(half4_t, u);
  o[0] = (float)h[0];
  o[1] = (float)h[1];
  o[2] = (float)h[2];
  o[3] = (float)h[3];
}

// Fused setup: [0,2048) edge prep | [2048,2208) weight prep | [2208,3744) fp32 table
__global__ __launch_bounds__(256) void k_setup(
    const float* __restrict__ pos, const int* __restrict__ esrc,
    const int* __restrict__ etgt, int* __restrict__ pk,
    const float* __restrict__ cf_w1, const float* __restrict__ cf_w2,
    const float* __restrict__ int_w, const float* __restrict__ out_w1,
    const float* __restrict__ out_w2, _Float16* __restrict__ PW,
    const float* __restrict__ w1, const float* __restrict__ b1,
    const float* __restrict__ w2, const float* __restrict__ b2,
    float* __restrict__ T, int* __restrict__ cnt) {
  __shared__ float g2[2][64];
  __shared__ float S2[2][128];
  const int b = blockIdx.x;
  const int tid = threadIdx.x;
  if (b == 0 && tid == 0) *cnt = 0;
  if (b < 2048) {
    int e = b * 256 + tid;
    int r = esrc[e], c = etgt[e];
    float dx = pos[r * 3 + 0] - pos[c * 3 + 0];
    float dy = pos[r * 3 + 1] - pos[c * 3 + 1];
    float dz = pos[r * 3 + 2] - pos[c * 3 + 2];
    float d = sqrtf(dx * dx + dy * dy + dz * dz);
    int i = (int)(d * ((float)(TPB - 1) / CUTOFF) + 0.5f);
    if (i > TPB - 1) i = TPB - 1;
    if (i < 0) i = 0;
    // low 20 bits: byte offset of table row (i*256); bits 20+: src local idx
    pk[e] = (i << 8) | ((r & (APC - 1)) << 20);
  } else if (b < 2208) {
    int e = (b - 2048) * 256 + tid;   // < 20*2048
    int g = e >> 11, t = e & 2047;
    int kb = t >> 9, rem = t & 511, nt = rem >> 6, lane = rem & 63;
    int quad = lane >> 4, ln = lane & 15;
    int kbase = kb * 32 + quad * 8;
    int n = nt * 16 + ln;
    const float* src;
    if (g < 12) {
      int l = g >> 1;
      src = (g & 1) ? (int_w + l * 16384) : (cf_w2 + l * 16384);
    } else if (g < 18) {
      src = cf_w1 + (g - 12) * 16384;
    } else {
      src = (g == 18) ? out_w1 : out_w2;
    }
    half8_t hv;
    #pragma unroll
    for (int j = 0; j < 8; j++) hv[j] = (_Float16)src[(kbase + j) * H + n];
    *(half8_t*)&PW[(size_t)g * 16384 + (size_t)t * 8] = hv;
  } else {
    int bb = b - 2208;
    const int l = bb >> 8;               // TP0/2 = 256 blocks/layer
    const int grp = tid >> 7;
    const int c = tid & 127;
    const int p = (bb & 255) * 2 + grp;
    const float d = (float)p * (CUTOFF / (float)(TP0 - 1));
    const float gspace = CUTOFF / (float)(G - 1);
    const float coeff = -0.5f / (gspace * gspace);
    if (c < G) {
      float x = d - (float)c * gspace;
      g2[grp][c] = __expf(coeff * x * x);
    }
    __syncthreads();
    const float* W1 = w1 + l * G * H;
    float s = b1[l * H + c];
    #pragma unroll 5
    for (int i = 0; i < G; i++) s += g2[grp][i] * W1[i * H + c];
    S2[grp][c] = ssp_f(s);
    __syncthreads();
    const float* W2 = w2 + l * H * H;
    float o = b2[l * H + c];
    #pragma unroll 8
    for (int j = 0; j < H; j++) o += S2[grp][j] * W2[j * H + c];
    float Cc = 0.5f * (__cosf(d * (3.14159265358979f / CUTOFF)) + 1.f);
    T[((size_t)l * TP0 + p) * H + c] = o * Cc;
  }
}

// upsample fp32 TP0 table -> fp16 TPB nearest table via lerp; 4 ch per thread.
// Output rows in SPLIT-PAIR layout: 16B slot s holds channels
// {4s..4s+3, 64+4s..64+4s+3}, matching k_mega's agg lane mapping.
__global__ __launch_bounds__(256) void k_up(const float* __restrict__ T,
                                            unsigned short* __restrict__ Tb) {
  int t = blockIdx.x * 256 + threadIdx.x;   // < NL*TPB*H/4
  int l = t >> 17;                          // TPB*H/4 = 131072
  int rem = t & 131071;
  int p4 = rem >> 5, cg = rem & 31;
  int c = cg * 4;
  float u = (float)p4 * ((float)(TP0 - 1) / (float)(TPB - 1));
  int i = (int)u;
  if (i > TP0 - 2) i = TP0 - 2;
  float f = u - (float)i;
  const float* a = T + ((size_t)l * TP0 + i) * H + c;
  float4 v0 = *(const float4*)a;
  float4 v1 = *(const float4*)(a + H);
  half4_t h;
  h[0] = (_Float16)(v0.x + f * (v1.x - v0.x));
  h[1] = (_Float16)(v0.y + f * (v1.y - v0.y));
  h[2] = (_Float16)(v0.z + f * (v1.z - v0.z));
  h[3] = (_Float16)(v0.w + f * (v1.w - v0.w));
  // split-pair slot: c<64 -> slot cg, halves 0..3; c>=64 -> slot cg-16, halves 4..7
  int dst = (cg < 16) ? cg * 8 : (cg - 16) * 8 + 4;
  *(uint2*)&Tb[((size_t)l * TPB + p4) * H + dst] = __builtin_bit_cast(uint2, h);
}

#define MFMA16(a, b, c) __builtin_amdgcn_mfma_f32_16x16x32_f16((a), (b), (c), 0, 0, 0)

// B fragments for one GEMM phase, prefetched into registers BEFORE the barrier
// that precedes the phase (T14 issue-early/consume-late).
struct BF {
  half8_t h[4];
};
__device__ __forceinline__ BF load_B(const _Float16* __restrict__ pw, int nt, int lane) {
  BF b;
  #pragma unroll
  for (int kb = 0; kb < 4; kb++)
    b.h[kb] = *(const half8_t*)(pw + ((size_t)(kb * 8 + nt) * 64 + lane) * 8);
  return b;
}

// wave handles 2 row-tiles (rt2 half) x 1 col-tile nt; single fp16 MFMA per
// (kb,rtt) — fp16's 2^-11 error sits below the nearest-table noise floor.
// UNSWAPPED variant (C-layout: lane owns col=ln, rows quad*4+reg) - readout G2.
__device__ __forceinline__ void gemm_rt2(const _Float16 (*A)[136],
                                         const BF& b, int rt2, int quad, int ln,
                                         f32x4 acc[2]) {
  #pragma unroll
  for (int kb = 0; kb < 4; kb++) {
    int ko = kb * 32 + quad * 8;
    #pragma unroll
    for (int rtt = 0; rtt < 2; rtt++) {
      int row = rt2 * 32 + rtt * 16 + ln;
      half8_t ah = *(const half8_t*)&A[row][ko];
      acc[rtt] = MFMA16(ah, b.h[kb], acc[rtt]);
    }
  }
}

// SWAPPED-operand variant: mfma(Bfrag, Afrag) computes the transposed tile,
// so lane (quad,ln) reg holds OUT[row = tile+ln][col = nt*16 + quad*4 + reg]
// -> packed b64 epilogues.
__device__ __forceinline__ void gemm_rt2T(const _Float16 (*A)[136],
                                          const BF& b, int rt2, int quad, int ln,
                                          f32x4 acc[2]) {
  #pragma unroll
  for (int kb = 0; kb < 4; kb++) {
    int ko = kb * 32 + quad * 8;
    #pragma unroll
    for (int rtt = 0; rtt < 2; rtt++) {
      int row = rt2 * 32 + rtt * 16 + ln;
      half8_t ah = *(const half8_t*)&A[row][ko];
      acc[rtt] = MFMA16(b.h[kb], ah, acc[rtt]);
    }
  }
}

// aggregation inner body: one b128 fp16 xs read per edge per lane. xs stride
// 128 halves = 64 words === 0 mod 32 -> bank phase independent of random sl
// (R4-verified split-pair property, restored). Storage types stay uint4
// (R7's no-spill codegen); bit_cast to half8_t only at the point of use.
// (float)h * (float)h -> v_fma_mix_f32.
#define AGG_BODY(A2, MSARR, TVARR)                                             \
  {                                                                            \
    float accs[8] = {0.f, 0.f, 0.f, 0.f, 0.f, 0.f, 0.f, 0.f};                  \
    _Pragma("unroll") for (int it = 0; it < 8; it++) {                         \
      int sl = MSARR[it] >> 20;                                                \
      uint4 xv4 = *(const uint4*)&xsp[sl * 128 + ln * 8];                      \
      half8_t xv = __builtin_bit_cast(half8_t, xv4);                           \
      half8_t tv = __builtin_bit_cast(half8_t, TVARR[it]);                     \
      _Pragma("unroll") for (int j = 0; j < 8; j++)                            \
        accs[j] += (float)tv[j] * (float)xv[j];                                \
    }                                                                          \
    _Pragma("unroll") for (int j = 0; j < 8; j++) {                            \
      accs[j] += __shfl_xor(accs[j], 16);                                      \
      accs[j] += __shfl_xor(accs[j], 32);                                      \
    }                                                                          \
    float va =                                                                 \
        eg == 0 ? accs[0] : eg == 1 ? accs[2] : eg == 2 ? accs[4] : accs[6];   \
    float vb =                                                                 \
        eg == 0 ? accs[1] : eg == 1 ? accs[3] : eg == 2 ? accs[5] : accs[7];   \
    half2_t hv2;                                                               \
    hv2[0] = (_Float16)va;                                                     \
    hv2[1] = (_Float16)vb;                                                     \
    int cw = (eg >> 1) * 64 + (ln * 4) + (eg & 1) * 2;                         \
    *(unsigned*)&S1[A2][cw] = __builtin_bit_cast(unsigned, hv2);               \
  }

// Persistent per-conformer kernel + fused mol pool/head in last block.
__global__ __launch_bounds__(1024, 1) void k_mega(
    const int* __restrict__ z, const float* __restrict__ emb,
    const int* __restrict__ pk, const unsigned short* __restrict__ Tb,
    const _Float16* __restrict__ PW, const float* __restrict__ cf_b2,
    const float* __restrict__ int_b, const float* __restrict__ out_b1,
    const float* __restrict__ out_b2, float* __restrict__ ce,
    const float* __restrict__ hw1, const float* __restrict__ hb1,
    const float* __restrict__ hw2, const float* __restrict__ hb2,
    int* __restrict__ cnt, float* __restrict__ outp) {
  // xs region: declared fp32[64][128] (32 KB) so the tail pool can reuse it as
  // the 64x128 fp32 mol buffer; during layers it holds xf as fp16 split-pair
  // rows of stride 128 halves (256 B, bank-aligned) in its first 16 KB.
  __shared__ float xs[64][128];
  __shared__ __align__(16) _Float16 hs[64][136];                  // h (fp16)
  __shared__ __align__(16) _Float16 ts[64][136];                  // t (fp16)
  __shared__ __align__(16) _Float16 S1[64][136];                  // agg (fp16)
  __shared__ int pks[2048];
  __shared__ float ps[2][128];
  __shared__ int is_last;
  _Float16* xsp = (_Float16*)&xs[0][0];
  const int conf = blockIdx.x;
  const int tid = threadIdx.x;
  const int lane = tid & 63, w = tid >> 6;       // 16 waves
  const int quad = lane >> 4, ln = lane & 15;
  const int rt2 = w & 1, nt = w >> 1;            // 2 row-halves x 8 col-tiles
  const int eg = lane >> 4;
  const int colb = nt * 16 + quad * 4;           // swapped-epilogue col base
  // fp16 split-pair xs offset for a 4-channel group starting at colb
  const int xso = (colb & 63) * 2 + ((colb >= 64) ? 4 : 0);

  pks[tid] = pk[conf * 2048 + tid];
  pks[tid + 1024] = pk[conf * 2048 + 1024 + tid];

  // init h from emb (fp16 single)
  {
    int r = tid >> 4, cb = (tid & 15) * 8;
    const float* src = emb + (size_t)z[conf * 64 + r] * H + cb;
    float4 v0 = *(const float4*)src, v1 = *(const float4*)(src + 4);
    half8_t hv;
    hv[0] = (_Float16)v0.x; hv[1] = (_Float16)v0.y;
    hv[2] = (_Float16)v0.z; hv[3] = (_Float16)v0.w;
    hv[4] = (_Float16)v1.x; hv[5] = (_Float16)v1.y;
    hv[6] = (_Float16)v1.z; hv[7] = (_Float16)v1.w;
    *(half8_t*)&hs[r][cb] = hv;
  }
  // prefetch xs0's B fragments under the h-init barrier
  BF bX = load_B(PW + (size_t)12 * 16384, nt, lane);
  __syncthreads();

  int msP[8];
  uint4 tvP[8];

  // xs0 = h @ cf_w1[0]  (swapped: packed fp16 split-pair store per rtt)
  {
    f32x4 acc[2] = {{0.f, 0.f, 0.f, 0.f}, {0.f, 0.f, 0.f, 0.f}};
    gemm_rt2T(hs, bX, rt2, quad, ln, acc);
    #pragma unroll
    for (int rtt = 0; rtt < 2; rtt++)
      *(uint2*)&xsp[(rt2 * 32 + rtt * 16 + ln) * 128 + xso] = pack4h(acc[rtt]);
  }
  // prefetch first agg gather (layer 0) under the xs-ready barrier
  {
    const char* T0 = (const char*)Tb + ln * 16;
    #pragma unroll
    for (int it = 0; it < 8; it++) {
      msP[it] = pks[(w * 4) * DEG + it * 4 + eg];
      tvP[it] = *(const uint4*)(T0 + (msP[it] & 0xFFFFF));
    }
  }
  __syncthreads();

  BF bN;   // carries the B fragments for the phase after the next barrier

  for (int l = 0; l < NL; l++) {
    // split-pair Tb row: slot ln holds ch {4ln..4ln+3, 64+4ln..64+4ln+3}
    const char* Tlb = (const char*)(Tb + (size_t)l * TPB * H) + ln * 16;
    // ---- aggregation: aa=0 consumes the prefetched gather ----
    AGG_BODY(w * 4, msP, tvP)
    #pragma unroll 1
    for (int aa = 1; aa < 4; aa++) {
      int a2 = w * 4 + aa;
      int ms[8];
      uint4 tvv[8];
      #pragma unroll
      for (int it = 0; it < 8; it++) {
        ms[it] = pks[a2 * DEG + it * 4 + eg];
        tvv[it] = *(const uint4*)(Tlb + (ms[it] & 0xFFFFF));
      }
      AGG_BODY(a2, ms, tvv)
    }
    bN = load_B(PW + (size_t)(2 * l) * 16384, nt, lane);    // G1's B
    __syncthreads();
    // ---- GEMM1: t = ssp(S1 @ cf_w2[l] + cf_b2[l])  (swapped epilogue) ----
    {
      f32x4 acc[2] = {{0.f, 0.f, 0.f, 0.f}, {0.f, 0.f, 0.f, 0.f}};
      gemm_rt2T(S1, bN, rt2, quad, ln, acc);
      f32x4 bb4 = *(const f32x4*)&cf_b2[l * H + colb];
      #pragma unroll
      for (int rtt = 0; rtt < 2; rtt++) {
        int row = rt2 * 32 + rtt * 16 + ln;
        f32x4 v;
        #pragma unroll
        for (int reg = 0; reg < 4; reg++) v[reg] = ssp_f(acc[rtt][reg] + bb4[reg]);
        *(uint2*)&ts[row][colb] = pack4h(v);
      }
    }
    bN = load_B(PW + (size_t)(2 * l + 1) * 16384, nt, lane);  // G2's B
    __syncthreads();
    // ---- GEMM2: h += t @ int_w[l] + int_b[l]  (packed residual) ----
    {
      f32x4 acc[2] = {{0.f, 0.f, 0.f, 0.f}, {0.f, 0.f, 0.f, 0.f}};
      gemm_rt2T(ts, bN, rt2, quad, ln, acc);
      f32x4 bb4 = *(const f32x4*)&int_b[l * H + colb];
      #pragma unroll
      for (int rtt = 0; rtt < 2; rtt++) {
        int row = rt2 * 32 + rtt * 16 + ln;
        float hv[4];
        unpack4h(*(const uint2*)&hs[row][colb], hv);
        f32x4 v;
        #pragma unroll
        for (int reg = 0; reg < 4; reg++)
          v[reg] = acc[rtt][reg] + bb4[reg] + hv[reg];
        *(uint2*)&hs[row][colb] = pack4h(v);
      }
    }
    // next phase is GEMM3 (l<NL-1) or readout-G1 (l==NL-1)
    bN = load_B(PW + (size_t)((l < NL - 1) ? (13 + l) : 18) * 16384, nt, lane);
    __syncthreads();
    // ---- GEMM3: xs = h @ cf_w1[l+1]  (packed fp16 split-pair store) ----
    if (l < NL - 1) {
      f32x4 acc[2] = {{0.f, 0.f, 0.f, 0.f}, {0.f, 0.f, 0.f, 0.f}};
      gemm_rt2T(hs, bN, rt2, quad, ln, acc);
      #pragma unroll
      for (int rtt = 0; rtt < 2; rtt++)
        *(uint2*)&xsp[(rt2 * 32 + rtt * 16 + ln) * 128 + xso] = pack4h(acc[rtt]);
      // prefetch next layer's first agg gather under this barrier
      const char* Tn = (const char*)(Tb + (size_t)(l + 1) * TPB * H) + ln * 16;
      #pragma unroll
      for (int it = 0; it < 8; it++) {
        msP[it] = pks[(w * 4) * DEG + it * 4 + eg];
        tvP[it] = *(const uint4*)(Tn + (msP[it] & 0xFFFFF));
      }
      __syncthreads();
    }
  }

  // here bN holds PW[18] (loaded at l=NL-1 before the last barrier)
  // ---- readout GEMM1: t = ssp(h @ out_w1 + out_b1)  (swapped epilogue) ----
  {
    f32x4 acc[2] = {{0.f, 0.f, 0.f, 0.f}, {0.f, 0.f, 0.f, 0.f}};
    gemm_rt2T(hs, bN, rt2, quad, ln, acc);
    f32x4 bb4 = *(const f32x4*)&out_b1[colb];
    #pragma unroll
    for (int rtt = 0; rtt < 2; rtt++) {
      int row = rt2 * 32 + rtt * 16 + ln;
      f32x4 v;
      #pragma unroll
      for (int reg = 0; reg < 4; reg++) v[reg] = ssp_f(acc[rtt][reg] + bb4[reg]);
      *(uint2*)&ts[row][colb] = pack4h(v);
    }
  }
  bN = load_B(PW + (size_t)19 * 16384, nt, lane);
  __syncthreads();
  // ---- readout GEMM2 + row-sum pool (unswapped orientation) ----
  {
    f32x4 acc[2] = {{0.f, 0.f, 0.f, 0.f}, {0.f, 0.f, 0.f, 0.f}};
    gemm_rt2(ts, bN, rt2, quad, ln, acc);
    int col = nt * 16 + ln;
    float s = acc[0][0] + acc[0][1] + acc[0][2] + acc[0][3] +
              acc[1][0] + acc[1][1] + acc[1][2] + acc[1][3];
    s += __shfl_xor(s, 16);
    s += __shfl_xor(s, 32);
    if (quad == 0) ps[rt2][col] = s;
  }
  __syncthreads();
  if (tid < 128) {
    float v = ps[0][tid] + ps[1][tid] + 64.f * out_b2[tid];
    __hip_atomic_store(&ce[conf * 128 + tid], v, __ATOMIC_RELAXED,
                       __HIP_MEMORY_SCOPE_AGENT);
  }
  __syncthreads();
  if (tid == 0) {
    __threadfence();
    int old = __hip_atomic_fetch_add(cnt, 1, __ATOMIC_ACQ_REL,
                                     __HIP_MEMORY_SCOPE_AGENT);
    is_last = (old == N_CONF - 1) ? 1 : 0;
  }
  __syncthreads();
  if (is_last) {
    __threadfence();
    float* mol = &xs[0][0];        // 64*128 fp32 region (32 KB)
    for (int t = tid; t < N_MOL * 128; t += 1024) {
      int m = t >> 7, c = t & 127;
      const float* b = ce + (size_t)(m * 4) * 128;
      float s = __hip_atomic_load(&b[c], __ATOMIC_RELAXED, __HIP_MEMORY_SCOPE_AGENT) +
                __hip_atomic_load(&b[128 + c], __ATOMIC_RELAXED, __HIP_MEMORY_SCOPE_AGENT) +
                __hip_atomic_load(&b[256 + c], __ATOMIC_RELAXED, __HIP_MEMORY_SCOPE_AGENT) +
                __hip_atomic_load(&b[384 + c], __ATOMIC_RELAXED, __HIP_MEMORY_SCOPE_AGENT);
      mol[t] = s;
    }
    __syncthreads();
    float* q = (float*)&S1[0][0];  // 64*64 fp32 region (16 KB <= 17.4 KB)
    for (int t = tid; t < N_MOL * 64; t += 1024) {
      int m = t >> 6, j = t & 63;
      float qq = hb1[j];
      #pragma unroll 8
      for (int c = 0; c < H; c++) qq += mol[m * 128 + c] * hw1[c * 64 + j];
      q[t] = ssp_f(qq);
    }
    __syncthreads();
    if (tid < N_MOL) {
      float o = hb2[0];
      #pragma unroll 8
      for (int j = 0; j < 64; j++) o += q[tid * 64 + j] * hw2[j];
      outp[tid] = o;
    }
  }
}

extern "C" void kernel_launch(void* const* d_in, const int* in_sizes, int n_in,
                              void* d_out, int out_size, void* d_ws, size_t ws_size,
                              hipStream_t stream) {
  const int*   z       = (const int*)d_in[0];
  const float* pos     = (const float*)d_in[1];
  const int*   eidx    = (const int*)d_in[2];
  const float* emb     = (const float*)d_in[5];
  const float* mlp_w1  = (const float*)d_in[6];
  const float* mlp_b1  = (const float*)d_in[7];
  const float* mlp_w2  = (const float*)d_in[8];
  const float* mlp_b2  = (const float*)d_in[9];
  const float* cf_w1   = (const float*)d_in[10];
  const float* cf_w2   = (const float*)d_in[11];
  const float* cf_b2   = (const float*)d_in[12];
  const float* int_w   = (const float*)d_in[13];
  const float* int_b   = (const float*)d_in[14];
  const float* out_w1  = (const float*)d_in[15];
  const float* out_b1  = (const float*)d_in[16];
  const float* out_w2  = (const float*)d_in[17];
  const float* out_b2  = (const float*)d_in[18];
  const float* head_w1 = (const float*)d_in[19];
  const float* head_b1 = (const float*)d_in[20];
  const float* head_w2 = (const float*)d_in[21];
  const float* head_b2 = (const float*)d_in[22];

  char* ws = (char*)d_ws;
  float*          T   = (float*)ws;                                  // NL*TP0*H
  unsigned short* Tb  = (unsigned short*)(ws + (size_t)NL * TP0 * H * 4);
  char*           p2  = (char*)Tb + (size_t)NL * TPB * H * 2;
  int*            pk  = (int*)p2;
  _Float16*       PW  = (_Float16*)(p2 + (size_t)NEDGE * 4);
  float*          ce  = (float*)((char*)PW + (size_t)20 * 16384 * 2);
  int*            cnt = (int*)((char*)ce + (size_t)N_CONF * H * 4);

  k_setup<<<3744, 256, 0, stream>>>(pos, eidx, eidx + NEDGE, pk,
                                    cf_w1, cf_w2, int_w, out_w1, out_w2, PW,
                                    mlp_w1, mlp_b1, mlp_w2, mlp_b2, T, cnt);
  k_up<<<(NL * TPB * H / 4) / 256, 256, 0, stream>>>(T, Tb);

  k_mega<<<N_CONF, 1024, 0, stream>>>(z, emb, pk, Tb, PW, cf_b2, int_b,
                                      out_b1, out_b2, ce,
                                      head_w1, head_b1, head_w2, head_b2,
                                      cnt, (float*)d_out);
}

// Round 13
// 214.850 us; speedup vs baseline: 1.0901x; 1.0901x over previous
//
#include <hip/hip_runtime.h>
#include <math.h>

#define N_ATOMS 16384
#define APC 64
#define N_CONF 256
#define N_MOL 64
#define DEG 32
#define NEDGE (N_ATOMS * DEG)
#define H 128
#define G 50
#define NL 6
#define TP0 512          // fp32 source table points
#define TPB 4096         // bf16 nearest table points
#define CUTOFF 10.0f

typedef __attribute__((ext_vector_type(8))) short short8_t;
typedef __attribute__((ext_vector_type(8))) _Float16 half8_t;
typedef __attribute__((ext_vector_type(4))) float f32x4;
typedef __attribute__((ext_vector_type(2))) float f32x2;

__device__ __forceinline__ float ssp_f(float x) {
  float e = __expf(-fabsf(x));
  return fmaxf(x, 0.f) + __logf(1.f + e) - 0.69314718055994531f;
}
__device__ __forceinline__ unsigned short bf16_rne(float x) {
  unsigned u = __float_as_uint(x);
  unsigned r = u + 0x7FFF + ((u >> 16) & 1);
  return (unsigned short)(r >> 16);
}
__device__ __forceinline__ float bf16_to_f(unsigned short s) {
  return __uint_as_float(((unsigned)s) << 16);
}
__device__ __forceinline__ float bflo(unsigned u) { return __uint_as_float(u << 16); }
__device__ __forceinline__ float bfhi(unsigned u) { return __uint_as_float(u & 0xFFFF0000u); }

// pack 4 fp32 -> 4 fp16 (RNE) in a uint2
__device__ __forceinline__ uint2 pack4h(const f32x4 v) {
  union { _Float16 h[4]; uint2 u; } x;
  x.h[0] = (_Float16)v[0];
  x.h[1] = (_Float16)v[1];
  x.h[2] = (_Float16)v[2];
  x.h[3] = (_Float16)v[3];
  return x.u;
}
__device__ __forceinline__ void unpack4h(uint2 u, float* o) {
  union { uint2 u; _Float16 h[4]; } x;
  x.u = u;
  o[0] = (float)x.h[0];
  o[1] = (float)x.h[1];
  o[2] = (float)x.h[2];
  o[3] = (float)x.h[3];
}

// Fused setup: [0,2048) edge prep | [2048,2208) weight prep | [2208,3744) fp32 table
__global__ __launch_bounds__(256) void k_setup(
    const float* __restrict__ pos, const int* __restrict__ esrc,
    const int* __restrict__ etgt, int* __restrict__ pk,
    const float* __restrict__ cf_w1, const float* __restrict__ cf_w2,
    const float* __restrict__ int_w, const float* __restrict__ out_w1,
    const float* __restrict__ out_w2, _Float16* __restrict__ PW,
    const float* __restrict__ w1, const float* __restrict__ b1,
    const float* __restrict__ w2, const float* __restrict__ b2,
    float* __restrict__ T, int* __restrict__ cnt) {
  __shared__ float g2[2][64];
  __shared__ float S2[2][128];
  const int b = blockIdx.x;
  const int tid = threadIdx.x;
  if (b == 0 && tid == 0) *cnt = 0;
  if (b < 2048) {
    int e = b * 256 + tid;
    int r = esrc[e], c = etgt[e];
    float dx = pos[r * 3 + 0] - pos[c * 3 + 0];
    float dy = pos[r * 3 + 1] - pos[c * 3 + 1];
    float dz = pos[r * 3 + 2] - pos[c * 3 + 2];
    float d = sqrtf(dx * dx + dy * dy + dz * dz);
    int i = (int)(d * ((float)(TPB - 1) / CUTOFF) + 0.5f);
    if (i > TPB - 1) i = TPB - 1;
    if (i < 0) i = 0;
    // low 20 bits: byte offset of table row (i*256); bits 20+: src local idx
    pk[e] = (i << 8) | ((r & (APC - 1)) << 20);
  } else if (b < 2208) {
    int e = (b - 2048) * 256 + tid;   // < 20*2048
    int g = e >> 11, t = e & 2047;
    int kb = t >> 9, rem = t & 511, nt = rem >> 6, lane = rem & 63;
    int quad = lane >> 4, ln = lane & 15;
    int kbase = kb * 32 + quad * 8;
    int n = nt * 16 + ln;
    const float* src;
    if (g < 12) {
      int l = g >> 1;
      src = (g & 1) ? (int_w + l * 16384) : (cf_w2 + l * 16384);
    } else if (g < 18) {
      src = cf_w1 + (g - 12) * 16384;
    } else {
      src = (g == 18) ? out_w1 : out_w2;
    }
    half8_t hv;
    #pragma unroll
    for (int j = 0; j < 8; j++) hv[j] = (_Float16)src[(kbase + j) * H + n];
    *(half8_t*)&PW[(size_t)g * 16384 + (size_t)t * 8] = hv;
  } else {
    int bb = b - 2208;
    const int l = bb >> 8;               // TP0/2 = 256 blocks/layer
    const int grp = tid >> 7;
    const int c = tid & 127;
    const int p = (bb & 255) * 2 + grp;
    const float d = (float)p * (CUTOFF / (float)(TP0 - 1));
    const float gspace = CUTOFF / (float)(G - 1);
    const float coeff = -0.5f / (gspace * gspace);
    if (c < G) {
      float x = d - (float)c * gspace;
      g2[grp][c] = __expf(coeff * x * x);
    }
    __syncthreads();
    const float* W1 = w1 + l * G * H;
    float s = b1[l * H + c];
    #pragma unroll 5
    for (int i = 0; i < G; i++) s += g2[grp][i] * W1[i * H + c];
    S2[grp][c] = ssp_f(s);
    __syncthreads();
    const float* W2 = w2 + l * H * H;
    float o = b2[l * H + c];
    #pragma unroll 8
    for (int j = 0; j < H; j++) o += S2[grp][j] * W2[j * H + c];
    float Cc = 0.5f * (__cosf(d * (3.14159265358979f / CUTOFF)) + 1.f);
    T[((size_t)l * TP0 + p) * H + c] = o * Cc;
  }
}

// upsample fp32 TP0 table -> bf16 TPB nearest table via lerp; 4 ch per thread.
// Output rows in SPLIT-PAIR layout: 16B slot s holds channels
// {4s..4s+3, 64+4s..64+4s+3}, so k_mega's xs gather is bank-uniform.
__global__ __launch_bounds__(256) void k_up(const float* __restrict__ T,
                                            unsigned short* __restrict__ Tb) {
  int t = blockIdx.x * 256 + threadIdx.x;   // < NL*TPB*H/4
  int l = t >> 17;                          // TPB*H/4 = 131072
  int rem = t & 131071;
  int p4 = rem >> 5, cg = rem & 31;
  int c = cg * 4;
  float u = (float)p4 * ((float)(TP0 - 1) / (float)(TPB - 1));
  int i = (int)u;
  if (i > TP0 - 2) i = TP0 - 2;
  float f = u - (float)i;
  const float* a = T + ((size_t)l * TP0 + i) * H + c;
  float4 v0 = *(const float4*)a;
  float4 v1 = *(const float4*)(a + H);
  ushort4 o;
  o.x = bf16_rne(v0.x + f * (v1.x - v0.x));
  o.y = bf16_rne(v0.y + f * (v1.y - v0.y));
  o.z = bf16_rne(v0.z + f * (v1.z - v0.z));
  o.w = bf16_rne(v0.w + f * (v1.w - v0.w));
  // split-pair slot: c<64 -> slot cg, shorts 0..3; c>=64 -> slot cg-16, shorts 4..7
  int dst = (cg < 16) ? cg * 8 : (cg - 16) * 8 + 4;
  *(ushort4*)&Tb[((size_t)l * TPB + p4) * H + dst] = o;
}

#define MFMA16(a, b, c) __builtin_amdgcn_mfma_f32_16x16x32_f16((a), (b), (c), 0, 0, 0)

// B fragments for one GEMM phase, prefetched into registers BEFORE the barrier
// that precedes the phase (T14 issue-early/consume-late).
struct BF {
  half8_t h[4];
};
__device__ __forceinline__ BF load_B(const _Float16* __restrict__ pw, int nt, int lane) {
  BF b;
  #pragma unroll
  for (int kb = 0; kb < 4; kb++)
    b.h[kb] = *(const half8_t*)(pw + ((size_t)(kb * 8 + nt) * 64 + lane) * 8);
  return b;
}

// wave handles 2 row-tiles (rt2 half) x 1 col-tile nt; single fp16 MFMA per
// (kb,rtt) — fp16's 2^-11 error sits below the nearest-table noise floor.
// UNSWAPPED variant (C-layout: lane owns col=ln, rows quad*4+reg) - readout G2.
__device__ __forceinline__ void gemm_rt2(const _Float16 (*A)[136],
                                         const BF& b, int rt2, int quad, int ln,
                                         f32x4 acc[2]) {
  #pragma unroll
  for (int kb = 0; kb < 4; kb++) {
    int ko = kb * 32 + quad * 8;
    #pragma unroll
    for (int rtt = 0; rtt < 2; rtt++) {
      int row = rt2 * 32 + rtt * 16 + ln;
      half8_t ah = *(const half8_t*)&A[row][ko];
      acc[rtt] = MFMA16(ah, b.h[kb], acc[rtt]);
    }
  }
}

// SWAPPED-operand variant: mfma(Bfrag, Afrag) computes the transposed tile,
// so lane (quad,ln) reg holds OUT[row = tile+ln][col = nt*16 + quad*4 + reg]
// -> packed b64 epilogues.
__device__ __forceinline__ void gemm_rt2T(const _Float16 (*A)[136],
                                          const BF& b, int rt2, int quad, int ln,
                                          f32x4 acc[2]) {
  #pragma unroll
  for (int kb = 0; kb < 4; kb++) {
    int ko = kb * 32 + quad * 8;
    #pragma unroll
    for (int rtt = 0; rtt < 2; rtt++) {
      int row = rt2 * 32 + rtt * 16 + ln;
      half8_t ah = *(const half8_t*)&A[row][ko];
      acc[rtt] = MFMA16(b.h[kb], ah, acc[rtt]);
    }
  }
}

// aggregation inner body (MSARR/TVARR must be statically-indexed arrays)
#define AGG_BODY(A2, MSARR, TVARR)                                             \
  {                                                                            \
    f32x2 ac0 = {0.f, 0.f}, ac1 = {0.f, 0.f}, ac2 = {0.f, 0.f},                \
          ac3 = {0.f, 0.f};                                                    \
    _Pragma("unroll") for (int it = 0; it < 8; it++) {                         \
      int sl = MSARR[it] >> 20;                                                \
      const float* xr = &xs[sl][c0];                                           \
      float4 x0 = *(const float4*)xr;                                          \
      float4 x1 = *(const float4*)(xr + 64);                                   \
      uint4 tv = TVARR[it];                                                    \
      ac0 = __builtin_elementwise_fma((f32x2){bflo(tv.x), bfhi(tv.x)},         \
                                      (f32x2){x0.x, x0.y}, ac0);               \
      ac1 = __builtin_elementwise_fma((f32x2){bflo(tv.y), bfhi(tv.y)},         \
                                      (f32x2){x0.z, x0.w}, ac1);               \
      ac2 = __builtin_elementwise_fma((f32x2){bflo(tv.z), bfhi(tv.z)},         \
                                      (f32x2){x1.x, x1.y}, ac2);               \
      ac3 = __builtin_elementwise_fma((f32x2){bflo(tv.w), bfhi(tv.w)},         \
                                      (f32x2){x1.z, x1.w}, ac3);               \
    }                                                                          \
    float accs[8] = {ac0.x, ac0.y, ac1.x, ac1.y, ac2.x, ac2.y, ac3.x, ac3.y};  \
    _Pragma("unroll") for (int j = 0; j < 8; j++) {                            \
      accs[j] += __shfl_xor(accs[j], 16);                                      \
      accs[j] += __shfl_xor(accs[j], 32);                                      \
    }                                                                          \
    float va =                                                                 \
        eg == 0 ? accs[0] : eg == 1 ? accs[2] : eg == 2 ? accs[4] : accs[6];   \
    float vb =                                                                 \
        eg == 0 ? accs[1] : eg == 1 ? accs[3] : eg == 2 ? accs[5] : accs[7];   \
    union { _Float16 h[2]; short2 s; } uu;                                     \
    uu.h[0] = (_Float16)va;                                                    \
    uu.h[1] = (_Float16)vb;                                                    \
    int cw = (eg >> 1) * 64 + c0 + (eg & 1) * 2;                               \
    *(short2*)&S1[A2][cw] = uu.s;                                              \
  }

// Persistent per-conformer kernel + fused mol pool/head in last block.
__global__ __launch_bounds__(1024, 1) void k_mega(
    const int* __restrict__ z, const float* __restrict__ emb,
    const int* __restrict__ pk, const unsigned short* __restrict__ Tb,
    const _Float16* __restrict__ PW, const float* __restrict__ cf_b2,
    const float* __restrict__ int_b, const float* __restrict__ out_b1,
    const float* __restrict__ out_b2, float* __restrict__ ce,
    const float* __restrict__ hw1, const float* __restrict__ hb1,
    const float* __restrict__ hw2, const float* __restrict__ hb2,
    int* __restrict__ cnt, float* __restrict__ outp) {
  // xs stride 128 words === 0 mod 32: gather bank = f(lane) only (split-pair).
  __shared__ float xs[64][128];                                   // xf, fp32
  __shared__ __align__(16) _Float16 hs[64][136];                  // h (fp16)
  __shared__ __align__(16) _Float16 ts[64][136];                  // t (fp16)
  __shared__ __align__(16) _Float16 S1[64][136];                  // agg (fp16)
  __shared__ int pks[2048];
  __shared__ float ps[2][128];
  __shared__ int is_last;
  const int conf = blockIdx.x;
  const int tid = threadIdx.x;
  const int lane = tid & 63, w = tid >> 6;       // 16 waves
  const int quad = lane >> 4, ln = lane & 15;
  const int rt2 = w & 1, nt = w >> 1;            // 2 row-halves x 8 col-tiles
  const int eg = lane >> 4, c0 = (lane & 15) * 4;
  const int colb = nt * 16 + quad * 4;           // swapped-epilogue col base

  pks[tid] = pk[conf * 2048 + tid];
  pks[tid + 1024] = pk[conf * 2048 + 1024 + tid];

  // init h from emb (fp16 single)
  {
    int r = tid >> 4, cb = (tid & 15) * 8;
    const float* src = emb + (size_t)z[conf * 64 + r] * H + cb;
    float4 v0 = *(const float4*)src, v1 = *(const float4*)(src + 4);
    half8_t hv;
    hv[0] = (_Float16)v0.x; hv[1] = (_Float16)v0.y;
    hv[2] = (_Float16)v0.z; hv[3] = (_Float16)v0.w;
    hv[4] = (_Float16)v1.x; hv[5] = (_Float16)v1.y;
    hv[6] = (_Float16)v1.z; hv[7] = (_Float16)v1.w;
    *(half8_t*)&hs[r][cb] = hv;
  }
  // prefetch xs0's B fragments under the h-init barrier
  BF bX = load_B(PW + (size_t)12 * 16384, nt, lane);
  __syncthreads();

  int msP[8];
  uint4 tvP[8];

  // xs0 = h @ cf_w1[0]  (swapped: float4 store per rtt)
  {
    f32x4 acc[2] = {{0.f, 0.f, 0.f, 0.f}, {0.f, 0.f, 0.f, 0.f}};
    gemm_rt2T(hs, bX, rt2, quad, ln, acc);
    #pragma unroll
    for (int rtt = 0; rtt < 2; rtt++)
      *(f32x4*)&xs[rt2 * 32 + rtt * 16 + ln][colb] = acc[rtt];
  }
  // prefetch first agg gather (layer 0) under the xs-ready barrier
  {
    const char* T0 = (const char*)Tb + ln * 16;
    #pragma unroll
    for (int it = 0; it < 8; it++) {
      msP[it] = pks[(w * 4) * DEG + it * 4 + eg];
      tvP[it] = *(const uint4*)(T0 + (msP[it] & 0xFFFFF));
    }
  }
  __syncthreads();

  BF bN;   // carries the B fragments for the phase after the next barrier

  for (int l = 0; l < NL; l++) {
    // split-pair Tb row: slot ln holds ch {4ln..4ln+3, 64+4ln..64+4ln+3}
    const char* Tlb = (const char*)(Tb + (size_t)l * TPB * H) + ln * 16;
    // ---- aggregation: aa=0 consumes the prefetched gather ----
    AGG_BODY(w * 4, msP, tvP)
    #pragma unroll 1
    for (int aa = 1; aa < 4; aa++) {
      int a2 = w * 4 + aa;
      int ms[8];
      uint4 tvv[8];
      #pragma unroll
      for (int it = 0; it < 8; it++) {
        ms[it] = pks[a2 * DEG + it * 4 + eg];
        tvv[it] = *(const uint4*)(Tlb + (ms[it] & 0xFFFFF));
      }
      AGG_BODY(a2, ms, tvv)
    }
    bN = load_B(PW + (size_t)(2 * l) * 16384, nt, lane);    // G1's B
    __syncthreads();
    // ---- GEMM1: t = ssp(S1 @ cf_w2[l] + cf_b2[l])  (swapped epilogue) ----
    {
      f32x4 acc[2] = {{0.f, 0.f, 0.f, 0.f}, {0.f, 0.f, 0.f, 0.f}};
      gemm_rt2T(S1, bN, rt2, quad, ln, acc);
      f32x4 bb4 = *(const f32x4*)&cf_b2[l * H + colb];
      #pragma unroll
      for (int rtt = 0; rtt < 2; rtt++) {
        int row = rt2 * 32 + rtt * 16 + ln;
        f32x4 v;
        #pragma unroll
        for (int reg = 0; reg < 4; reg++) v[reg] = ssp_f(acc[rtt][reg] + bb4[reg]);
        *(uint2*)&ts[row][colb] = pack4h(v);
      }
    }
    bN = load_B(PW + (size_t)(2 * l + 1) * 16384, nt, lane);  // G2's B
    __syncthreads();
    // ---- GEMM2: h += t @ int_w[l] + int_b[l]  (packed residual) ----
    {
      f32x4 acc[2] = {{0.f, 0.f, 0.f, 0.f}, {0.f, 0.f, 0.f, 0.f}};
      gemm_rt2T(ts, bN, rt2, quad, ln, acc);
      f32x4 bb4 = *(const f32x4*)&int_b[l * H + colb];
      #pragma unroll
      for (int rtt = 0; rtt < 2; rtt++) {
        int row = rt2 * 32 + rtt * 16 + ln;
        float hv[4];
        unpack4h(*(const uint2*)&hs[row][colb], hv);
        f32x4 v;
        #pragma unroll
        for (int reg = 0; reg < 4; reg++)
          v[reg] = acc[rtt][reg] + bb4[reg] + hv[reg];
        *(uint2*)&hs[row][colb] = pack4h(v);
      }
    }
    // next phase is GEMM3 (l<NL-1) or readout-G1 (l==NL-1)
    bN = load_B(PW + (size_t)((l < NL - 1) ? (13 + l) : 18) * 16384, nt, lane);
    __syncthreads();
    // ---- GEMM3: xs = h @ cf_w1[l+1]  (float4 store) ----
    if (l < NL - 1) {
      f32x4 acc[2] = {{0.f, 0.f, 0.f, 0.f}, {0.f, 0.f, 0.f, 0.f}};
      gemm_rt2T(hs, bN, rt2, quad, ln, acc);
      #pragma unroll
      for (int rtt = 0; rtt < 2; rtt++)
        *(f32x4*)&xs[rt2 * 32 + rtt * 16 + ln][colb] = acc[rtt];
      // prefetch next layer's first agg gather under this barrier
      const char* Tn = (const char*)(Tb + (size_t)(l + 1) * TPB * H) + ln * 16;
      #pragma unroll
      for (int it = 0; it < 8; it++) {
        msP[it] = pks[(w * 4) * DEG + it * 4 + eg];
        tvP[it] = *(const uint4*)(Tn + (msP[it] & 0xFFFFF));
      }
      __syncthreads();
    }
  }

  // here bN holds PW[18] (loaded at l=NL-1 before the last barrier)
  // ---- readout GEMM1: t = ssp(h @ out_w1 + out_b1)  (swapped epilogue) ----
  {
    f32x4 acc[2] = {{0.f, 0.f, 0.f, 0.f}, {0.f, 0.f, 0.f, 0.f}};
    gemm_rt2T(hs, bN, rt2, quad, ln, acc);
    f32x4 bb4 = *(const f32x4*)&out_b1[colb];
    #pragma unroll
    for (int rtt = 0; rtt < 2; rtt++) {
      int row = rt2 * 32 + rtt * 16 + ln;
      f32x4 v;
      #pragma unroll
      for (int reg = 0; reg < 4; reg++) v[reg] = ssp_f(acc[rtt][reg] + bb4[reg]);
      *(uint2*)&ts[row][colb] = pack4h(v);
    }
  }
  bN = load_B(PW + (size_t)19 * 16384, nt, lane);
  __syncthreads();
  // ---- readout GEMM2 + row-sum pool (unswapped orientation) ----
  {
    f32x4 acc[2] = {{0.f, 0.f, 0.f, 0.f}, {0.f, 0.f, 0.f, 0.f}};
    gemm_rt2(ts, bN, rt2, quad, ln, acc);
    int col = nt * 16 + ln;
    float s = acc[0][0] + acc[0][1] + acc[0][2] + acc[0][3] +
              acc[1][0] + acc[1][1] + acc[1][2] + acc[1][3];
    s += __shfl_xor(s, 16);
    s += __shfl_xor(s, 32);
    if (quad == 0) ps[rt2][col] = s;
  }
  __syncthreads();
  if (tid < 128) {
    float v = ps[0][tid] + ps[1][tid] + 64.f * out_b2[tid];
    __hip_atomic_store(&ce[conf * 128 + tid], v, __ATOMIC_RELAXED,
                       __HIP_MEMORY_SCOPE_AGENT);
  }
  __syncthreads();
  if (tid == 0) {
    __threadfence();
    int old = __hip_atomic_fetch_add(cnt, 1, __ATOMIC_ACQ_REL,
                                     __HIP_MEMORY_SCOPE_AGENT);
    is_last = (old == N_CONF - 1) ? 1 : 0;
  }
  __syncthreads();
  if (is_last) {
    __threadfence();
    float* mol = &xs[0][0];        // 64*128 region
    for (int t = tid; t < N_MOL * 128; t += 1024) {
      int m = t >> 7, c = t & 127;
      const float* b = ce + (size_t)(m * 4) * 128;
      float s = __hip_atomic_load(&b[c], __ATOMIC_RELAXED, __HIP_MEMORY_SCOPE_AGENT) +
                __hip_atomic_load(&b[128 + c], __ATOMIC_RELAXED, __HIP_MEMORY_SCOPE_AGENT) +
                __hip_atomic_load(&b[256 + c], __ATOMIC_RELAXED, __HIP_MEMORY_SCOPE_AGENT) +
                __hip_atomic_load(&b[384 + c], __ATOMIC_RELAXED, __HIP_MEMORY_SCOPE_AGENT);
      mol[t] = s;
    }
    __syncthreads();
    float* q = (float*)&S1[0][0];  // 64*64 fp32 region (16 KB <= 17.4 KB)
    for (int t = tid; t < N_MOL * 64; t += 1024) {
      int m = t >> 6, j = t & 63;
      float qq = hb1[j];
      #pragma unroll 8
      for (int c = 0; c < H; c++) qq += mol[m * 128 + c] * hw1[c * 64 + j];
      q[t] = ssp_f(qq);
    }
    __syncthreads();
    if (tid < N_MOL) {
      float o = hb2[0];
      #pragma unroll 8
      for (int j = 0; j < 64; j++) o += q[tid * 64 + j] * hw2[j];
      outp[tid] = o;
    }
  }
}

extern "C" void kernel_launch(void* const* d_in, const int* in_sizes, int n_in,
                              void* d_out, int out_size, void* d_ws, size_t ws_size,
                              hipStream_t stream) {
  const int*   z       = (const int*)d_in[0];
  const float* pos     = (const float*)d_in[1];
  const int*   eidx    = (const int*)d_in[2];
  const float* emb     = (const float*)d_in[5];
  const float* mlp_w1  = (const float*)d_in[6];
  const float* mlp_b1  = (const float*)d_in[7];
  const float* mlp_w2  = (const float*)d_in[8];
  const float* mlp_b2  = (const float*)d_in[9];
  const float* cf_w1   = (const float*)d_in[10];
  const float* cf_w2   = (const float*)d_in[11];
  const float* cf_b2   = (const float*)d_in[12];
  const float* int_w   = (const float*)d_in[13];
  const float* int_b   = (const float*)d_in[14];
  const float* out_w1  = (const float*)d_in[15];
  const float* out_b1  = (const float*)d_in[16];
  const float* out_w2  = (const float*)d_in[17];
  const float* out_b2  = (const float*)d_in[18];
  const float* head_w1 = (const float*)d_in[19];
  const float* head_b1 = (const float*)d_in[20];
  const float* head_w2 = (const float*)d_in[21];
  const float* head_b2 = (const float*)d_in[22];

  char* ws = (char*)d_ws;
  float*          T   = (float*)ws;                                  // NL*TP0*H
  unsigned short* Tb  = (unsigned short*)(ws + (size_t)NL * TP0 * H * 4);
  char*           p2  = (char*)Tb + (size_t)NL * TPB * H * 2;
  int*            pk  = (int*)p2;
  _Float16*       PW  = (_Float16*)(p2 + (size_t)NEDGE * 4);
  float*          ce  = (float*)((char*)PW + (size_t)20 * 16384 * 2);
  int*            cnt = (int*)((char*)ce + (size_t)N_CONF * H * 4);

  k_setup<<<3744, 256, 0, stream>>>(pos, eidx, eidx + NEDGE, pk,
                                    cf_w1, cf_w2, int_w, out_w1, out_w2, PW,
                                    mlp_w1, mlp_b1, mlp_w2, mlp_b2, T, cnt);
  k_up<<<(NL * TPB * H / 4) / 256, 256, 0, stream>>>(T, Tb);

  k_mega<<<N_CONF, 1024, 0, stream>>>(z, emb, pk, Tb, PW, cf_b2, int_b,
                                      out_b1, out_b2, ce,
                                      head_w1, head_b1, head_w2, head_b2,
                                      cnt, (float*)d_out);
}